// Round 16
// baseline (299.721 us; speedup 1.0000x reference)
//
#include <hip/hip_runtime.h>
#include <cmath>

#define DIM_  1024
#define NH_   16
#define DH_   64
#define NL_   3
#define NK_   4
#define B_    2
#define T_    2048
#define OFFC_ (NH_ * NL_ * NK_)   // 192
#define KDIM  1024

typedef __attribute__((ext_vector_type(8))) __bf16 bf16x8;
typedef __attribute__((ext_vector_type(4))) float f32x4;

__device__ __forceinline__ unsigned short f2bf(float f) {
  unsigned u = __float_as_uint(f);
  u += 0x7FFFu + ((u >> 16) & 1u);
  return (unsigned short)(u >> 16);
}
__device__ __forceinline__ float bf2f(unsigned short s) {
  return __uint_as_float((unsigned)s << 16);
}
__device__ __forceinline__ void glds16(const void* g, void* l) {
  __builtin_amdgcn_global_load_lds((const __attribute__((address_space(1))) void*)g,
                                   (__attribute__((address_space(3))) void*)l, 16, 0, 0);
}
// LDS chunk swizzle (involution): validated r8 (SQ_LDS_BANK_CONFLICT 3.1M -> 0)
__device__ __forceinline__ int swz(int c) { return c ^ ((c >> 3) & 7); }

// ================= mega-prep: x-cvt | biases | weight transposes (4 k-tiles per block) =======
__global__ __launch_bounds__(256) void prep_kernel(
    const float* __restrict__ x,
    const float* __restrict__ Wq, const float* __restrict__ Wk,
    const float* __restrict__ Wv, const float* __restrict__ Wo,
    const float* __restrict__ Woff,
    const float* __restrict__ bq, const float* __restrict__ bk,
    const float* __restrict__ bv, const float* __restrict__ bo,
    const float* __restrict__ boff,
    unsigned short* __restrict__ xcat,
    unsigned short* __restrict__ Btcat, unsigned short* __restrict__ Wofft,
    float* __restrict__ biascat, float* __restrict__ boffp) {
  __shared__ float tile[32][33];
  const int p = blockIdx.x;
  const int tid = threadIdx.x;

  if (p < 1024) {
    int b = p >> 9, t4 = p & 511;
#pragma unroll
    for (int r = 0; r < 4; ++r) {
      float4 a = *(const float4*)(x + (size_t)((b * T_ + 4 * t4 + r)) * DIM_ + tid * 4);
      ushort4 hi, lo;
      hi.x = f2bf(a.x); hi.y = f2bf(a.y); hi.z = f2bf(a.z); hi.w = f2bf(a.w);
      lo.x = f2bf(a.x - bf2f(hi.x)); lo.y = f2bf(a.y - bf2f(hi.y));
      lo.z = f2bf(a.z - bf2f(hi.z)); lo.w = f2bf(a.w - bf2f(hi.w));
      size_t base = (size_t)(b * T_ + 4 * t4 + r) * 3072 + tid * 4;
      *(ushort4*)(xcat + base) = hi;
      *(ushort4*)(xcat + base + 1024) = lo;
      *(ushort4*)(xcat + base + 2048) = hi;
    }
  } else if (p < 1041) {
    int i = (p - 1024) * 256 + tid;
    if (i < 4096) {
      float v;
      if (i < 1024) v = bq[i];
      else if (i < 2048) v = bk[i - 1024];
      else if (i < 3072) v = bv[i - 2048];
      else v = bo[i - 3072];
      biascat[i] = v;
    } else if (i < 4352) {
      int j = i - 4096;
      boffp[j] = (j < OFFC_) ? boff[j] : 0.0f;
    }
  } else if (p < 2065) {
    int q = p - 1041;                  // 0..1023
    int z = q >> 8, q2 = q & 255;
    const float* Ws = (z == 0) ? Wq : (z == 1) ? Wk : (z == 2) ? Wv : Wo;
    unsigned short* Wd = Btcat + (size_t)z * 1024 * 1024;
    int kg = q2 & 7, n0 = (q2 >> 3) * 32;
    int tx = tid & 31, ty = tid >> 5;
#pragma unroll
    for (int kk = 0; kk < 4; ++kk) {
      int k0 = kg * 128 + kk * 32;
#pragma unroll
      for (int r = 0; r < 32; r += 8)
        tile[ty + r][tx] = Ws[(size_t)(k0 + ty + r) * KDIM + n0 + tx];
      __syncthreads();
#pragma unroll
      for (int r = 0; r < 32; r += 8)
        Wd[(size_t)(n0 + ty + r) * KDIM + k0 + tx] = f2bf(tile[tx][ty + r]);
      __syncthreads();
    }
  } else {
    int q3 = p - 2065;                 // 0..63
    int kg = q3 & 7, n0 = (q3 >> 3) * 32;
    int tx = tid & 31, ty = tid >> 5;
#pragma unroll
    for (int kk = 0; kk < 4; ++kk) {
      int k0 = kg * 128 + kk * 32;
#pragma unroll
      for (int r = 0; r < 32; r += 8) {
        int nn = n0 + tx;
        tile[ty + r][tx] = (nn < OFFC_) ? Woff[(size_t)(k0 + ty + r) * OFFC_ + nn] : 0.0f;
      }
      __syncthreads();
#pragma unroll
      for (int r = 0; r < 32; r += 8) {
        float v = tile[tx][ty + r];
        unsigned short hi = f2bf(v);
        unsigned short lo = f2bf(v - bf2f(hi));
        size_t n = (size_t)(n0 + ty + r);
        Wofft[n * 3072 + k0 + tx] = hi;
        Wofft[n * 3072 + 1024 + k0 + tx] = hi;
        Wofft[n * 3072 + 2048 + k0 + tx] = lo;
      }
      __syncthreads();
    }
  }
}

// ---------------- grouped bf16 MFMA GEMM + fused kv-pyramid epilogue ----------------
struct Epi {
  void* ptr[4];
  void* d1[4];     // optional: pair-avg level-1 output (bf16), null = skip
  void* d2[4];     // optional: level-2 output (bf16)
  int start[4];
  int ldc[4];
  int width[4];
  int nseg;
  int bf16_mask;
  int tanh_mask;
};
struct Group {
  const unsigned short* A;   // [M][lda] bf16 bits
  const unsigned short* Bt;  // [N][K] bf16 bits
  const float* bias;         // [N]
  Epi epi;
  int K, lda;
  int blk0, nby;             // first flat block id, M/BM (col-major block order)
};
struct GArgs { Group g[3]; int ng; };

// BK=64; 128x256 tile for the big dispatch: 64 MFMA per barrier (2x r15) to amortize the
// vmcnt(0)+s_barrier drain at K=1024 (16 K-iters/block). m105: 128x256 within 10% of 128^2
// at K=4096; at K=1024 barrier-amortization dominates.
template <int BM, int BN>
__global__ __launch_bounds__(256) void gemm_grouped_kernel(GArgs ga) {
  constexpr int BK = 64;
  constexpr int MI = BM / 32, MJ = BN / 32;
  constexpr int CPR = BK / 8;
  constexpr int TCA = BM * CPR;
  constexpr int R = (BM + BN) * CPR / 256;
  __shared__ __align__(16) unsigned short lds_s[(BM + BN) * BK];

  int gi = 0;
#pragma unroll
  for (int s = 1; s < 3; ++s)
    if (s < ga.ng && (int)blockIdx.x >= ga.g[s].blk0) gi = s;
  const unsigned short* A  = ga.g[gi].A;
  const unsigned short* Bt = ga.g[gi].Bt;
  const float* bias = ga.g[gi].bias;
  const int K = ga.g[gi].K, lda = ga.g[gi].lda;
  const int bflat = blockIdx.x - ga.g[gi].blk0;
  const int nby = ga.g[gi].nby;
  const int row0 = (bflat % nby) * BM, col0 = (bflat / nby) * BN;

  const int tid = threadIdx.x;
  const int lane = tid & 63;
  const int wv = tid >> 6;
  const int wm = wv & 1, wn = wv >> 1;
  const int q = lane >> 4, jj = lane & 15;

  const unsigned short* gP[R];
  unsigned short* lP[R];
#pragma unroll
  for (int r = 0; r < R; ++r) {
    int l = r * 256 + tid;
    int c = swz(l);
    lP[r] = lds_s + l * 8;
    if (c < TCA)
      gP[r] = A + (size_t)(row0 + (c >> 3)) * lda + (c & 7) * 8;
    else {
      int c2 = c - TCA;
      gP[r] = Bt + (size_t)(col0 + (c2 >> 3)) * K + (c2 & 7) * 8;
    }
  }

  int aoff[2][MI], boff[2][MJ];
#pragma unroll
  for (int h = 0; h < 2; ++h) {
#pragma unroll
    for (int i = 0; i < MI; ++i)
      aoff[h][i] = swz((wm * (BM / 2) + i * 16 + jj) * CPR + h * 4 + q) * 8;
#pragma unroll
    for (int j = 0; j < MJ; ++j)
      boff[h][j] = (TCA + swz((wn * (BN / 2) + j * 16 + jj) * CPR + h * 4 + q)) * 8;
  }

  f32x4 acc[MI][MJ] = {};

  for (int k0 = 0; k0 < K; k0 += BK) {
#pragma unroll
    for (int r = 0; r < R; ++r) glds16(gP[r] + k0, lP[r]);
    __syncthreads();
#pragma unroll
    for (int h = 0; h < 2; ++h) {
      bf16x8 af[MI], bfr[MJ];
#pragma unroll
      for (int i = 0; i < MI; ++i) af[i] = *(const bf16x8*)(lds_s + aoff[h][i]);
#pragma unroll
      for (int j = 0; j < MJ; ++j) bfr[j] = *(const bf16x8*)(lds_s + boff[h][j]);
#pragma unroll
      for (int i = 0; i < MI; ++i)
#pragma unroll
        for (int j = 0; j < MJ; ++j)
          acc[i][j] = __builtin_amdgcn_mfma_f32_16x16x32_bf16(af[i], bfr[j], acc[i][j], 0, 0, 0);
    }
    __syncthreads();
  }

  const Epi& epi = ga.g[gi].epi;
  int sIdx = 0;
#pragma unroll
  for (int s = 1; s < 4; ++s)
    if (s < epi.nseg && col0 >= epi.start[s]) sIdx = s;
  const int st = epi.start[sIdx], ld = epi.ldc[sIdx], wdt = epi.width[sIdx];
  const bool isBf = (epi.bf16_mask >> sIdx) & 1;
  const bool doTanh = (epi.tanh_mask >> sIdx) & 1;
  float* opf = (float*)epi.ptr[sIdx];
  unsigned short* opb = (unsigned short*)epi.ptr[sIdx];
  unsigned short* pd1 = (unsigned short*)epi.d1[sIdx];
  unsigned short* pd2 = (unsigned short*)epi.d2[sIdx];

#pragma unroll
  for (int i = 0; i < MI; ++i) {
    int rbase = row0 + wm * (BM / 2) + i * 16 + q * 4;   // multiple of 4
#pragma unroll
    for (int j = 0; j < MJ; ++j) {
      int ccol = col0 + wn * (BN / 2) + j * 16 + jj;
      int lc = ccol - st;
      if (lc < wdt) {
        float bsv = bias[ccol];
        float vv[4];
#pragma unroll
        for (int p = 0; p < 4; ++p) {
          float v = acc[i][j][p] + bsv;
          if (doTanh) v = tanhf(v) * 0.25f;
          vv[p] = v;
          size_t oi = (size_t)(rbase + p) * ld + lc;
          if (isBf) opb[oi] = f2bf(v);
          else      opf[oi] = v;
        }
        if (pd1) {
          float a01 = 0.5f * (vv[0] + vv[1]);
          float a23 = 0.5f * (vv[2] + vv[3]);
          pd1[(size_t)(rbase >> 1) * ld + lc] = f2bf(a01);
          pd1[(size_t)((rbase >> 1) + 1) * ld + lc] = f2bf(a23);
          pd2[(size_t)(rbase >> 2) * ld + lc] = f2bf(0.5f * (a01 + a23));
        }
      }
    }
  }
}

// ---------------- attention: 32 lanes per (b,t,h), samples split 6+6; relative RoPE ----------
__global__ __launch_bounds__(256) void attn_kernel(
    const unsigned short* __restrict__ qb, const float* __restrict__ off,
    const unsigned short* __restrict__ k0, const unsigned short* __restrict__ k1,
    const unsigned short* __restrict__ k2,
    const unsigned short* __restrict__ v0, const unsigned short* __restrict__ v1,
    const unsigned short* __restrict__ v2,
    unsigned short* __restrict__ out) {
  const int nb8 = gridDim.x >> 3;
  int sb = ((blockIdx.x & 7) * nb8) + (blockIdx.x >> 3);
  int gid = sb * 256 + threadIdx.x;
  int l32 = gid & 31;
  int li  = l32 & 15;
  int sh  = l32 >> 4;
  int tup = gid >> 5;
  int h   = tup >> 12;
  int bt  = tup & 4095;
  int t   = bt & (T_ - 1);
  int b   = bt >> 11;
  const bool firstHalf = (li & 8) == 0;

  float invf[4];
#pragma unroll
  for (int j = 0; j < 4; ++j)
    invf[j] = exp2f(-(float)(4 * (li & 7) + j) * (13.287712379549449f / 32.0f));

  const int col = h * DH_ + li * 4;
  ushort4 qu = *(const ushort4*)(qb + (size_t)bt * DIM_ + col);
  float q4[4] = {bf2f(qu.x), bf2f(qu.y), bf2f(qu.z), bf2f(qu.w)};

  const float refp = (float)t * (1.0f / (float)(T_ - 1));
  const float* offp = off + (size_t)bt * OFFC_ + h * (NL_ * NK_);
  const float tf = (float)t;

  float sum = 0.0f;
  float o4[4] = {0.0f, 0.0f, 0.0f, 0.0f};

#pragma unroll
  for (int j = 0; j < 6; ++j) {
    const int lvA = (j >= 4) ? 1 : 0;
    const int lvB = (j < 2) ? 1 : 2;
    const int TsA = T_ >> lvA, TsB = T_ >> lvB;
    const int Ts = sh ? TsB : TsA;
    const unsigned short* kl = sh ? ((lvB == 1) ? k1 : k2) : ((lvA == 0) ? k0 : k1);
    const unsigned short* vl = sh ? ((lvB == 1) ? v1 : v2) : ((lvA == 0) ? v0 : v1);
    const int s = (sh ? 6 : 0) + j;

    float ofv = offp[s];
    float sn = fminf(fmaxf(refp + ofv, 0.0f), 1.0f);
    float idx = fminf(sn * (float)(Ts - 1), (float)(Ts - 1) - 1e-6f);
    int i0 = (int)idx;
    int i1 = min(i0 + 1, Ts - 1);
    float w1 = idx - (float)i0, w0 = 1.0f - w1;
    size_t r0 = (size_t)(b * Ts + i0) * DIM_ + col;
    size_t r1 = (size_t)(b * Ts + i1) * DIM_ + col;
    const ushort4 ka = *(const ushort4*)(kl + r0);
    const ushort4 kb = *(const ushort4*)(kl + r1);
    float kx[4] = {w0 * bf2f(ka.x) + w1 * bf2f(kb.x), w0 * bf2f(ka.y) + w1 * bf2f(kb.y),
                   w0 * bf2f(ka.z) + w1 * bf2f(kb.z), w0 * bf2f(ka.w) + w1 * bf2f(kb.w)};
    float rel = idx - tf;
    float p = 0.0f;
#pragma unroll
    for (int jd = 0; jd < 4; ++jd) {
      float pr = __shfl_xor(kx[jd], 8);
      float ang = rel * invf[jd];
      float si = __sinf(ang), co = __cosf(ang);
      float rk = firstHalf ? (kx[jd] * co - pr * si) : (pr * si + kx[jd] * co);
      p += q4[jd] * rk;
    }
#pragma unroll
    for (int m = 8; m > 0; m >>= 1) p += __shfl_xor(p, m);
    float e = __expf(p * 0.125f);
    sum += e;
    const ushort4 va = *(const ushort4*)(vl + r0);
    const ushort4 vb = *(const ushort4*)(vl + r1);
    o4[0] += e * (w0 * bf2f(va.x) + w1 * bf2f(vb.x));
    o4[1] += e * (w0 * bf2f(va.y) + w1 * bf2f(vb.y));
    o4[2] += e * (w0 * bf2f(va.z) + w1 * bf2f(vb.z));
    o4[3] += e * (w0 * bf2f(va.w) + w1 * bf2f(vb.w));
  }

  sum += __shfl_xor(sum, 16);
#pragma unroll
  for (int d = 0; d < 4; ++d) o4[d] += __shfl_xor(o4[d], 16);

  if (sh == 0) {
    float r = 1.0f / sum;
    ushort4 ou;
    ou.x = f2bf(o4[0] * r); ou.y = f2bf(o4[1] * r);
    ou.z = f2bf(o4[2] * r); ou.w = f2bf(o4[3] * r);
    *(ushort4*)(out + (size_t)bt * DIM_ + col) = ou;
  }
}

// ---------------- launch ----------------
extern "C" void kernel_launch(void* const* d_in, const int* in_sizes, int n_in,
                              void* d_out, int out_size, void* d_ws, size_t ws_size,
                              hipStream_t stream) {
  const float* x    = (const float*)d_in[0];
  const float* Wq   = (const float*)d_in[2];
  const float* bq   = (const float*)d_in[3];
  const float* Wk   = (const float*)d_in[4];
  const float* bk   = (const float*)d_in[5];
  const float* Wv   = (const float*)d_in[6];
  const float* bv   = (const float*)d_in[7];
  const float* Woff = (const float*)d_in[8];
  const float* boff = (const float*)d_in[9];
  const float* Wo   = (const float*)d_in[10];
  const float* bo   = (const float*)d_in[11];
  float* out = (float*)d_out;

  char* w = (char*)d_ws;
  auto alloc = [&](size_t bytes) { char* p = w; w += (bytes + 255) & ~(size_t)255; return p; };
  unsigned short* xcat  = (unsigned short*)alloc((size_t)4096 * 3072 * 2);
  unsigned short* ao_bf = xcat;   // overlays dead xcat after GEMMs
  unsigned short* q_bf  = (unsigned short*)alloc((size_t)4096 * 1024 * 2);
  unsigned short* Btcat = (unsigned short*)alloc((size_t)4096 * 1024 * 2);
  unsigned short* Wofft = (unsigned short*)alloc((size_t)256 * 3072 * 2);
  float* biascat = (float*)alloc((size_t)4096 * 4);
  float* boffp   = (float*)alloc((size_t)256 * 4);
  float* offb = (float*)alloc((size_t)4096 * 192 * 4);
  unsigned short* k1b = (unsigned short*)alloc((size_t)2048 * 1024 * 2);
  unsigned short* k2b = (unsigned short*)alloc((size_t)1024 * 1024 * 2);
  unsigned short* v1b = (unsigned short*)alloc((size_t)2048 * 1024 * 2);
  unsigned short* v2b = (unsigned short*)alloc((size_t)1024 * 1024 * 2);
  unsigned short* k0b = (unsigned short*)alloc((size_t)4096 * 1024 * 2);
  unsigned short* v0b = (unsigned short*)alloc((size_t)4096 * 1024 * 2);

  dim3 b256(256);

  // mega-prep
  prep_kernel<<<2129, b256, 0, stream>>>(x, Wq, Wk, Wv, Wo, Woff, bq, bk, bv, bo, boff,
                                         xcat, Btcat, Wofft, biascat, boffp);

  // Grouped GEMM, 128x256 tiles: [offset(32 blks, K=3072)] + [G1(384) w/ fused kv pyramid]
  GArgs ga = {};
  ga.g[0].A = xcat; ga.g[0].Bt = Wofft; ga.g[0].bias = boffp;
  ga.g[0].K = 3072; ga.g[0].lda = 3072; ga.g[0].blk0 = 0; ga.g[0].nby = 32;
  ga.g[0].epi.ptr[0] = offb; ga.g[0].epi.start[0] = 0; ga.g[0].epi.ldc[0] = 192;
  ga.g[0].epi.width[0] = 192; ga.g[0].epi.nseg = 1;
  ga.g[0].epi.bf16_mask = 0; ga.g[0].epi.tanh_mask = 1;
  ga.g[1].A = xcat; ga.g[1].Bt = Btcat; ga.g[1].bias = biascat;
  ga.g[1].K = 1024; ga.g[1].lda = 3072; ga.g[1].blk0 = 32; ga.g[1].nby = 32;
  ga.g[1].epi.ptr[0] = q_bf; ga.g[1].epi.ptr[1] = k0b; ga.g[1].epi.ptr[2] = v0b;
  ga.g[1].epi.d1[1] = k1b;  ga.g[1].epi.d2[1] = k2b;
  ga.g[1].epi.d1[2] = v1b;  ga.g[1].epi.d2[2] = v2b;
  ga.g[1].epi.start[0] = 0; ga.g[1].epi.start[1] = 1024; ga.g[1].epi.start[2] = 2048;
  ga.g[1].epi.ldc[0] = 1024; ga.g[1].epi.ldc[1] = 1024; ga.g[1].epi.ldc[2] = 1024;
  ga.g[1].epi.width[0] = 1024; ga.g[1].epi.width[1] = 1024; ga.g[1].epi.width[2] = 1024;
  ga.g[1].epi.nseg = 3; ga.g[1].epi.bf16_mask = 0x7; ga.g[1].epi.tanh_mask = 0;
  ga.ng = 2;
  gemm_grouped_kernel<128, 256><<<416, b256, 0, stream>>>(ga);

  // attention: 32 lanes/tuple -> 8192 blocks
  attn_kernel<<<(B_ * T_ * NH_ * 32) / 256, b256, 0, stream>>>(q_bf, offb, k0b, k1b, k2b,
                                                               v0b, v1b, v2b, ao_bf);

  // GEMM5: ao @ Wo  (M=4096, N=1024) -> fp32 out; 64x64 tiles = 1024 blocks
  GArgs g5 = {};
  g5.g[0].A = ao_bf; g5.g[0].Bt = Btcat + (size_t)3072 * 1024; g5.g[0].bias = biascat + 3072;
  g5.g[0].K = 1024; g5.g[0].lda = 1024; g5.g[0].blk0 = 0; g5.g[0].nby = 64;
  g5.g[0].epi.ptr[0] = out; g5.g[0].epi.start[0] = 0; g5.g[0].epi.ldc[0] = 1024;
  g5.g[0].epi.width[0] = 1024; g5.g[0].epi.nseg = 1;
  g5.g[0].epi.bf16_mask = 0; g5.g[0].epi.tanh_mask = 0;
  g5.ng = 1;
  gemm_grouped_kernel<64, 64><<<1024, b256, 0, stream>>>(g5);
}

// Round 17
// 226.456 us; speedup vs baseline: 1.3235x; 1.3235x over previous
//
#include <hip/hip_runtime.h>
#include <cmath>

#define DIM_  1024
#define NH_   16
#define DH_   64
#define NL_   3
#define NK_   4
#define B_    2
#define T_    2048
#define OFFC_ (NH_ * NL_ * NK_)   // 192
#define KDIM  1024

typedef __attribute__((ext_vector_type(8))) __bf16 bf16x8;
typedef __attribute__((ext_vector_type(4))) float f32x4;

__device__ __forceinline__ unsigned short f2bf(float f) {
  unsigned u = __float_as_uint(f);
  u += 0x7FFFu + ((u >> 16) & 1u);
  return (unsigned short)(u >> 16);
}
__device__ __forceinline__ float bf2f(unsigned short s) {
  return __uint_as_float((unsigned)s << 16);
}
__device__ __forceinline__ void glds16(const void* g, void* l) {
  __builtin_amdgcn_global_load_lds((const __attribute__((address_space(1))) void*)g,
                                   (__attribute__((address_space(3))) void*)l, 16, 0, 0);
}
// LDS chunk swizzle (involution): validated r8 (SQ_LDS_BANK_CONFLICT 3.1M -> 0)
__device__ __forceinline__ int swz(int c) { return c ^ ((c >> 3) & 7); }

// ================= mega-prep: x-cvt | biases | weight transposes (4 k-tiles per block) =======
// routing: [0,1024) x-prep; [1024,1041) biases; [1041,2065) Wq/Wk/Wv/Wo; [2065,2129) Woff
__global__ __launch_bounds__(256) void prep_kernel(
    const float* __restrict__ x,
    const float* __restrict__ Wq, const float* __restrict__ Wk,
    const float* __restrict__ Wv, const float* __restrict__ Wo,
    const float* __restrict__ Woff,
    const float* __restrict__ bq, const float* __restrict__ bk,
    const float* __restrict__ bv, const float* __restrict__ bo,
    const float* __restrict__ boff,
    unsigned short* __restrict__ xcat,
    unsigned short* __restrict__ Btcat, unsigned short* __restrict__ Wofft,
    float* __restrict__ biascat, float* __restrict__ boffp) {
  __shared__ float tile[32][33];
  const int p = blockIdx.x;
  const int tid = threadIdx.x;

  if (p < 1024) {
    int b = p >> 9, t4 = p & 511;
#pragma unroll
    for (int r = 0; r < 4; ++r) {
      float4 a = *(const float4*)(x + (size_t)((b * T_ + 4 * t4 + r)) * DIM_ + tid * 4);
      ushort4 hi, lo;
      hi.x = f2bf(a.x); hi.y = f2bf(a.y); hi.z = f2bf(a.z); hi.w = f2bf(a.w);
      lo.x = f2bf(a.x - bf2f(hi.x)); lo.y = f2bf(a.y - bf2f(hi.y));
      lo.z = f2bf(a.z - bf2f(hi.z)); lo.w = f2bf(a.w - bf2f(hi.w));
      size_t base = (size_t)(b * T_ + 4 * t4 + r) * 3072 + tid * 4;
      *(ushort4*)(xcat + base) = hi;
      *(ushort4*)(xcat + base + 1024) = lo;
      *(ushort4*)(xcat + base + 2048) = hi;
    }
  } else if (p < 1041) {
    int i = (p - 1024) * 256 + tid;
    if (i < 4096) {
      float v;
      if (i < 1024) v = bq[i];
      else if (i < 2048) v = bk[i - 1024];
      else if (i < 3072) v = bv[i - 2048];
      else v = bo[i - 3072];
      biascat[i] = v;
    } else if (i < 4352) {
      int j = i - 4096;
      boffp[j] = (j < OFFC_) ? boff[j] : 0.0f;
    }
  } else if (p < 2065) {
    // ---- Wq/Wk/Wv/Wo transpose+cast, 4 consecutive k-tiles per block ----
    int q = p - 1041;                  // 0..1023
    int z = q >> 8, q2 = q & 255;      // weight id; 8 k-groups x 32 n-tiles
    const float* Ws = (z == 0) ? Wq : (z == 1) ? Wk : (z == 2) ? Wv : Wo;
    unsigned short* Wd = Btcat + (size_t)z * 1024 * 1024;
    int kg = q2 & 7, n0 = (q2 >> 3) * 32;
    int tx = tid & 31, ty = tid >> 5;
#pragma unroll
    for (int kk = 0; kk < 4; ++kk) {
      int k0 = kg * 128 + kk * 32;
#pragma unroll
      for (int r = 0; r < 32; r += 8)
        tile[ty + r][tx] = Ws[(size_t)(k0 + ty + r) * KDIM + n0 + tx];
      __syncthreads();
#pragma unroll
      for (int r = 0; r < 32; r += 8)
        Wd[(size_t)(n0 + ty + r) * KDIM + k0 + tx] = f2bf(tile[tx][ty + r]);
      __syncthreads();
    }
  } else {
    // ---- Woff [1024][192] -> Wofft [256][3072] = [hi|hi|lo], 4 k-tiles per block ----
    int q3 = p - 2065;                 // 0..63: 8 k-groups x 8 n-tiles
    int kg = q3 & 7, n0 = (q3 >> 3) * 32;
    int tx = tid & 31, ty = tid >> 5;
#pragma unroll
    for (int kk = 0; kk < 4; ++kk) {
      int k0 = kg * 128 + kk * 32;
#pragma unroll
      for (int r = 0; r < 32; r += 8) {
        int nn = n0 + tx;
        tile[ty + r][tx] = (nn < OFFC_) ? Woff[(size_t)(k0 + ty + r) * OFFC_ + nn] : 0.0f;
      }
      __syncthreads();
#pragma unroll
      for (int r = 0; r < 32; r += 8) {
        float v = tile[tx][ty + r];
        unsigned short hi = f2bf(v);
        unsigned short lo = f2bf(v - bf2f(hi));
        size_t n = (size_t)(n0 + ty + r);
        Wofft[n * 3072 + k0 + tx] = hi;
        Wofft[n * 3072 + 1024 + k0 + tx] = hi;
        Wofft[n * 3072 + 2048 + k0 + tx] = lo;
      }
      __syncthreads();
    }
  }
}

// ---------------- grouped bf16 MFMA GEMM + fused kv-pyramid epilogue ----------------
struct Epi {
  void* ptr[4];
  void* d1[4];     // optional: pair-avg level-1 output (bf16), null = skip
  void* d2[4];     // optional: level-2 output (bf16)
  int start[4];
  int ldc[4];
  int width[4];
  int nseg;
  int bf16_mask;   // bit s: segment s stores bf16 (else fp32)
  int tanh_mask;   // bit s: tanh(.)*0.25
};
struct Group {
  const unsigned short* A;   // [M][lda] bf16 bits
  const unsigned short* Bt;  // [N][K] bf16 bits
  const float* bias;         // [N]
  Epi epi;
  int K, lda;
  int blk0, nby;             // first flat block id, M/BM (col-major block order)
};
struct GArgs { Group g[3]; int ng; };

// 128x128/BK=64/VGPR<=96 is the occupancy-feasible optimum for this structure:
// r16's 128x256 (VGPR 152, 48KB LDS) halved MfmaUtil; m132's BK=128 similarly regressed.
template <int BM, int BN>
__global__ __launch_bounds__(256) void gemm_grouped_kernel(GArgs ga) {
  constexpr int BK = 64;
  constexpr int MI = BM / 32, MJ = BN / 32;
  constexpr int CPR = BK / 8;
  constexpr int TCA = BM * CPR;
  constexpr int R = (BM + BN) * CPR / 256;
  __shared__ __align__(16) unsigned short lds_s[(BM + BN) * BK];

  int gi = 0;
#pragma unroll
  for (int s = 1; s < 3; ++s)
    if (s < ga.ng && (int)blockIdx.x >= ga.g[s].blk0) gi = s;
  const unsigned short* A  = ga.g[gi].A;
  const unsigned short* Bt = ga.g[gi].Bt;
  const float* bias = ga.g[gi].bias;
  const int K = ga.g[gi].K, lda = ga.g[gi].lda;
  const int bflat = blockIdx.x - ga.g[gi].blk0;
  const int nby = ga.g[gi].nby;
  const int row0 = (bflat % nby) * BM, col0 = (bflat / nby) * BN;

  const int tid = threadIdx.x;
  const int lane = tid & 63;
  const int wv = tid >> 6;
  const int wm = wv & 1, wn = wv >> 1;
  const int q = lane >> 4, jj = lane & 15;

  const unsigned short* gP[R];
  unsigned short* lP[R];
#pragma unroll
  for (int r = 0; r < R; ++r) {
    int l = r * 256 + tid;
    int c = swz(l);
    lP[r] = lds_s + l * 8;
    if (c < TCA)
      gP[r] = A + (size_t)(row0 + (c >> 3)) * lda + (c & 7) * 8;
    else {
      int c2 = c - TCA;
      gP[r] = Bt + (size_t)(col0 + (c2 >> 3)) * K + (c2 & 7) * 8;
    }
  }

  int aoff[2][MI], boff[2][MJ];
#pragma unroll
  for (int h = 0; h < 2; ++h) {
#pragma unroll
    for (int i = 0; i < MI; ++i)
      aoff[h][i] = swz((wm * (BM / 2) + i * 16 + jj) * CPR + h * 4 + q) * 8;
#pragma unroll
    for (int j = 0; j < MJ; ++j)
      boff[h][j] = (TCA + swz((wn * (BN / 2) + j * 16 + jj) * CPR + h * 4 + q)) * 8;
  }

  f32x4 acc[MI][MJ] = {};

  for (int k0 = 0; k0 < K; k0 += BK) {
#pragma unroll
    for (int r = 0; r < R; ++r) glds16(gP[r] + k0, lP[r]);
    __syncthreads();
#pragma unroll
    for (int h = 0; h < 2; ++h) {
      bf16x8 af[MI], bfr[MJ];
#pragma unroll
      for (int i = 0; i < MI; ++i) af[i] = *(const bf16x8*)(lds_s + aoff[h][i]);
#pragma unroll
      for (int j = 0; j < MJ; ++j) bfr[j] = *(const bf16x8*)(lds_s + boff[h][j]);
#pragma unroll
      for (int i = 0; i < MI; ++i)
#pragma unroll
        for (int j = 0; j < MJ; ++j)
          acc[i][j] = __builtin_amdgcn_mfma_f32_16x16x32_bf16(af[i], bfr[j], acc[i][j], 0, 0, 0);
    }
    __syncthreads();
  }

  const Epi& epi = ga.g[gi].epi;
  int sIdx = 0;
#pragma unroll
  for (int s = 1; s < 4; ++s)
    if (s < epi.nseg && col0 >= epi.start[s]) sIdx = s;
  const int st = epi.start[sIdx], ld = epi.ldc[sIdx], wdt = epi.width[sIdx];
  const bool isBf = (epi.bf16_mask >> sIdx) & 1;
  const bool doTanh = (epi.tanh_mask >> sIdx) & 1;
  float* opf = (float*)epi.ptr[sIdx];
  unsigned short* opb = (unsigned short*)epi.ptr[sIdx];
  unsigned short* pd1 = (unsigned short*)epi.d1[sIdx];
  unsigned short* pd2 = (unsigned short*)epi.d2[sIdx];

#pragma unroll
  for (int i = 0; i < MI; ++i) {
    int rbase = row0 + wm * (BM / 2) + i * 16 + q * 4;   // multiple of 4
#pragma unroll
    for (int j = 0; j < MJ; ++j) {
      int ccol = col0 + wn * (BN / 2) + j * 16 + jj;
      int lc = ccol - st;
      if (lc < wdt) {
        float bsv = bias[ccol];
        float vv[4];
#pragma unroll
        for (int p = 0; p < 4; ++p) {
          float v = acc[i][j][p] + bsv;
          if (doTanh) v = tanhf(v) * 0.25f;
          vv[p] = v;
          size_t oi = (size_t)(rbase + p) * ld + lc;
          if (isBf) opb[oi] = f2bf(v);
          else      opf[oi] = v;
        }
        if (pd1) {
          float a01 = 0.5f * (vv[0] + vv[1]);
          float a23 = 0.5f * (vv[2] + vv[3]);
          pd1[(size_t)(rbase >> 1) * ld + lc] = f2bf(a01);
          pd1[(size_t)((rbase >> 1) + 1) * ld + lc] = f2bf(a23);
          pd2[(size_t)(rbase >> 2) * ld + lc] = f2bf(0.5f * (a01 + a23));
        }
      }
    }
  }
}

// ---------------- attention: 32 lanes per (b,t,h), samples split 6+6; relative RoPE ----------
__global__ __launch_bounds__(256) void attn_kernel(
    const unsigned short* __restrict__ qb, const float* __restrict__ off,
    const unsigned short* __restrict__ k0, const unsigned short* __restrict__ k1,
    const unsigned short* __restrict__ k2,
    const unsigned short* __restrict__ v0, const unsigned short* __restrict__ v1,
    const unsigned short* __restrict__ v2,
    unsigned short* __restrict__ out) {
  const int nb8 = gridDim.x >> 3;
  int sb = ((blockIdx.x & 7) * nb8) + (blockIdx.x >> 3);
  int gid = sb * 256 + threadIdx.x;
  int l32 = gid & 31;
  int li  = l32 & 15;
  int sh  = l32 >> 4;            // sample-half
  int tup = gid >> 5;
  int h   = tup >> 12;           // head-major
  int bt  = tup & 4095;
  int t   = bt & (T_ - 1);
  int b   = bt >> 11;
  const bool firstHalf = (li & 8) == 0;

  float invf[4];
#pragma unroll
  for (int j = 0; j < 4; ++j)
    invf[j] = exp2f(-(float)(4 * (li & 7) + j) * (13.287712379549449f / 32.0f));

  const int col = h * DH_ + li * 4;
  ushort4 qu = *(const ushort4*)(qb + (size_t)bt * DIM_ + col);
  float q4[4] = {bf2f(qu.x), bf2f(qu.y), bf2f(qu.z), bf2f(qu.w)};

  const float refp = (float)t * (1.0f / (float)(T_ - 1));
  const float* offp = off + (size_t)bt * OFFC_ + h * (NL_ * NK_);
  const float tf = (float)t;

  float sum = 0.0f;
  float o4[4] = {0.0f, 0.0f, 0.0f, 0.0f};

#pragma unroll
  for (int j = 0; j < 6; ++j) {
    const int lvA = (j >= 4) ? 1 : 0;
    const int lvB = (j < 2) ? 1 : 2;
    const int TsA = T_ >> lvA, TsB = T_ >> lvB;
    const int Ts = sh ? TsB : TsA;
    const unsigned short* kl = sh ? ((lvB == 1) ? k1 : k2) : ((lvA == 0) ? k0 : k1);
    const unsigned short* vl = sh ? ((lvB == 1) ? v1 : v2) : ((lvA == 0) ? v0 : v1);
    const int s = (sh ? 6 : 0) + j;

    float ofv = offp[s];
    float sn = fminf(fmaxf(refp + ofv, 0.0f), 1.0f);
    float idx = fminf(sn * (float)(Ts - 1), (float)(Ts - 1) - 1e-6f);
    int i0 = (int)idx;
    int i1 = min(i0 + 1, Ts - 1);
    float w1 = idx - (float)i0, w0 = 1.0f - w1;
    size_t r0 = (size_t)(b * Ts + i0) * DIM_ + col;
    size_t r1 = (size_t)(b * Ts + i1) * DIM_ + col;
    const ushort4 ka = *(const ushort4*)(kl + r0);
    const ushort4 kb = *(const ushort4*)(kl + r1);
    float kx[4] = {w0 * bf2f(ka.x) + w1 * bf2f(kb.x), w0 * bf2f(ka.y) + w1 * bf2f(kb.y),
                   w0 * bf2f(ka.z) + w1 * bf2f(kb.z), w0 * bf2f(ka.w) + w1 * bf2f(kb.w)};
    float rel = idx - tf;
    float p = 0.0f;
#pragma unroll
    for (int jd = 0; jd < 4; ++jd) {
      float pr = __shfl_xor(kx[jd], 8);
      float ang = rel * invf[jd];
      float si = __sinf(ang), co = __cosf(ang);
      float rk = firstHalf ? (kx[jd] * co - pr * si) : (pr * si + kx[jd] * co);
      p += q4[jd] * rk;
    }
#pragma unroll
    for (int m = 8; m > 0; m >>= 1) p += __shfl_xor(p, m);
    float e = __expf(p * 0.125f);
    sum += e;
    const ushort4 va = *(const ushort4*)(vl + r0);
    const ushort4 vb = *(const ushort4*)(vl + r1);
    o4[0] += e * (w0 * bf2f(va.x) + w1 * bf2f(vb.x));
    o4[1] += e * (w0 * bf2f(va.y) + w1 * bf2f(vb.y));
    o4[2] += e * (w0 * bf2f(va.z) + w1 * bf2f(vb.z));
    o4[3] += e * (w0 * bf2f(va.w) + w1 * bf2f(vb.w));
  }

  sum += __shfl_xor(sum, 16);
#pragma unroll
  for (int d = 0; d < 4; ++d) o4[d] += __shfl_xor(o4[d], 16);

  if (sh == 0) {
    float r = 1.0f / sum;
    ushort4 ou;
    ou.x = f2bf(o4[0] * r); ou.y = f2bf(o4[1] * r);
    ou.z = f2bf(o4[2] * r); ou.w = f2bf(o4[3] * r);
    *(ushort4*)(out + (size_t)bt * DIM_ + col) = ou;
  }
}

// ---------------- launch ----------------
extern "C" void kernel_launch(void* const* d_in, const int* in_sizes, int n_in,
                              void* d_out, int out_size, void* d_ws, size_t ws_size,
                              hipStream_t stream) {
  const float* x    = (const float*)d_in[0];
  const float* Wq   = (const float*)d_in[2];
  const float* bq   = (const float*)d_in[3];
  const float* Wk   = (const float*)d_in[4];
  const float* bk   = (const float*)d_in[5];
  const float* Wv   = (const float*)d_in[6];
  const float* bv   = (const float*)d_in[7];
  const float* Woff = (const float*)d_in[8];
  const float* boff = (const float*)d_in[9];
  const float* Wo   = (const float*)d_in[10];
  const float* bo   = (const float*)d_in[11];
  float* out = (float*)d_out;

  char* w = (char*)d_ws;
  auto alloc = [&](size_t bytes) { char* p = w; w += (bytes + 255) & ~(size_t)255; return p; };
  unsigned short* xcat  = (unsigned short*)alloc((size_t)4096 * 3072 * 2);
  unsigned short* ao_bf = xcat;   // overlays dead xcat after GEMMs
  unsigned short* q_bf  = (unsigned short*)alloc((size_t)4096 * 1024 * 2);
  unsigned short* Btcat = (unsigned short*)alloc((size_t)4096 * 1024 * 2);
  unsigned short* Wofft = (unsigned short*)alloc((size_t)256 * 3072 * 2);
  float* biascat = (float*)alloc((size_t)4096 * 4);
  float* boffp   = (float*)alloc((size_t)256 * 4);
  float* offb = (float*)alloc((size_t)4096 * 192 * 4);
  unsigned short* k1b = (unsigned short*)alloc((size_t)2048 * 1024 * 2);
  unsigned short* k2b = (unsigned short*)alloc((size_t)1024 * 1024 * 2);
  unsigned short* v1b = (unsigned short*)alloc((size_t)2048 * 1024 * 2);
  unsigned short* v2b = (unsigned short*)alloc((size_t)1024 * 1024 * 2);
  unsigned short* k0b = (unsigned short*)alloc((size_t)4096 * 1024 * 2);
  unsigned short* v0b = (unsigned short*)alloc((size_t)4096 * 1024 * 2);

  dim3 b256(256);

  // mega-prep
  prep_kernel<<<2129, b256, 0, stream>>>(x, Wq, Wk, Wv, Wo, Woff, bq, bk, bv, bo, boff,
                                         xcat, Btcat, Wofft, biascat, boffp);

  // Grouped GEMM (128x128): [offset(64 blks, K=3072)] + [G1(768) w/ fused kv pyramid]
  GArgs ga = {};
  ga.g[0].A = xcat; ga.g[0].Bt = Wofft; ga.g[0].bias = boffp;
  ga.g[0].K = 3072; ga.g[0].lda = 3072; ga.g[0].blk0 = 0; ga.g[0].nby = 32;
  ga.g[0].epi.ptr[0] = offb; ga.g[0].epi.start[0] = 0; ga.g[0].epi.ldc[0] = 192;
  ga.g[0].epi.width[0] = 192; ga.g[0].epi.nseg = 1;
  ga.g[0].epi.bf16_mask = 0; ga.g[0].epi.tanh_mask = 1;
  ga.g[1].A = xcat; ga.g[1].Bt = Btcat; ga.g[1].bias = biascat;
  ga.g[1].K = 1024; ga.g[1].lda = 3072; ga.g[1].blk0 = 64; ga.g[1].nby = 32;
  ga.g[1].epi.ptr[0] = q_bf; ga.g[1].epi.ptr[1] = k0b; ga.g[1].epi.ptr[2] = v0b;
  ga.g[1].epi.d1[1] = k1b;  ga.g[1].epi.d2[1] = k2b;
  ga.g[1].epi.d1[2] = v1b;  ga.g[1].epi.d2[2] = v2b;
  ga.g[1].epi.start[0] = 0; ga.g[1].epi.start[1] = 1024; ga.g[1].epi.start[2] = 2048;
  ga.g[1].epi.ldc[0] = 1024; ga.g[1].epi.ldc[1] = 1024; ga.g[1].epi.ldc[2] = 1024;
  ga.g[1].epi.width[0] = 1024; ga.g[1].epi.width[1] = 1024; ga.g[1].epi.width[2] = 1024;
  ga.g[1].epi.nseg = 3; ga.g[1].epi.bf16_mask = 0x7; ga.g[1].epi.tanh_mask = 0;
  ga.ng = 2;
  gemm_grouped_kernel<128, 128><<<832, b256, 0, stream>>>(ga);

  // attention: 32 lanes/tuple -> 8192 blocks
  attn_kernel<<<(B_ * T_ * NH_ * 32) / 256, b256, 0, stream>>>(q_bf, offb, k0b, k1b, k2b,
                                                               v0b, v1b, v2b, ao_bf);

  // GEMM5: ao @ Wo  (M=4096, N=1024) -> fp32 out; 64x64 tiles = 1024 blocks
  GArgs g5 = {};
  g5.g[0].A = ao_bf; g5.g[0].Bt = Btcat + (size_t)3072 * 1024; g5.g[0].bias = biascat + 3072;
  g5.g[0].K = 1024; g5.g[0].lda = 1024; g5.g[0].blk0 = 0; g5.g[0].nby = 64;
  g5.g[0].epi.ptr[0] = out; g5.g[0].epi.start[0] = 0; g5.g[0].epi.ldc[0] = 1024;
  g5.g[0].epi.width[0] = 1024; g5.g[0].epi.nseg = 1;
  g5.g[0].epi.bf16_mask = 0; g5.g[0].epi.tanh_mask = 0;
  g5.ng = 1;
  gemm_grouped_kernel<64, 64><<<1024, b256, 0, stream>>>(g5);
}